// Round 9
// baseline (111.255 us; speedup 1.0000x reference)
//
#include <hip/hip_runtime.h>
#include <hip/hip_bf16.h>
#include <math.h>

#define EPS 1e-6f
#define PITCH 72    // bf16 elems per LDS row for weight tiles (64 K + 8 pad)
#define XPITCH 264  // bf16 elems per LDS row for full-K xm tile (256 + 8)

typedef short s16x8 __attribute__((ext_vector_type(8)));
typedef float f32x4 __attribute__((ext_vector_type(4)));

__device__ __forceinline__ short bf16of(float f) {
  __hip_bfloat16 h = __float2bfloat16(f);
  return __builtin_bit_cast(short, h);
}
__device__ __forceinline__ float f32of(unsigned short u) {
  unsigned int x = ((unsigned int)u) << 16;
  return __builtin_bit_cast(float, x);
}

// ---------------------------------------------------------------------------
// K1 (MFMA): y[m][p] = sum_c x[img][c][hw] * w1[p][c].  Output bf16.
// Block (0,0) also zero-inits the pooling accumulators (runs first in stream).
// ---------------------------------------------------------------------------
__global__ __launch_bounds__(256) void k_conv1x1(const float* __restrict__ x,
                                                 const float* __restrict__ w1,
                                                 short* __restrict__ ybf,
                                                 float* __restrict__ gsum,
                                                 unsigned int* __restrict__ gmaxu) {
  __shared__ __align__(16) short Aw[128 * PITCH];  // [p][k]
  __shared__ __align__(16) short Xs[64 * PITCH];   // [m][k]
  const int t = threadIdx.x;
  if (blockIdx.x == 0 && blockIdx.y == 0) {
#pragma unroll
    for (int i = 0; i < 4; ++i) {
      gsum[t + i * 256] = 0.f;
      gmaxu[t + i * 256] = 0u;
    }
  }
  const int m0 = blockIdx.x * 64, p0 = blockIdx.y * 128;
  const int img = m0 >> 12, hw0 = m0 & 4095;
  const int lane = t & 63, w = t >> 6;
  const int lrow = lane & 15, lk = (lane >> 4) * 8;
  f32x4 acc[4][2];
#pragma unroll
  for (int i = 0; i < 4; ++i)
#pragma unroll
    for (int j = 0; j < 2; ++j) acc[i][j] = {0.f, 0.f, 0.f, 0.f};

  for (int kk = 0; kk < 128; kk += 64) {
    __syncthreads();
    {  // stage w1 rows p0..p0+127
      const int pr = t & 127, kq = t >> 7;
      const float* wp = w1 + (size_t)(p0 + pr) * 128 + kk + kq * 32;
#pragma unroll
      for (int q = 0; q < 8; ++q) {
        const float4 v = *(const float4*)(wp + q * 4);
        short4 sv = {bf16of(v.x), bf16of(v.y), bf16of(v.z), bf16of(v.w)};
        *(short4*)(&Aw[pr * PITCH + kq * 32 + q * 4]) = sv;
      }
    }
    {  // stage x (c-major) -> Xs[m][c]: 4x4 register transpose
      const int m4 = (t & 15) * 4;
      const int cg = (t >> 4) * 4;
      float4 col[4];
#pragma unroll
      for (int cc = 0; cc < 4; ++cc)
        col[cc] = *(const float4*)(x + (size_t)(img * 128 + kk + cg + cc) * 4096 + hw0 + m4);
#pragma unroll
      for (int r = 0; r < 4; ++r) {
        short4 sv = {bf16of(((const float*)&col[0])[r]),
                     bf16of(((const float*)&col[1])[r]),
                     bf16of(((const float*)&col[2])[r]),
                     bf16of(((const float*)&col[3])[r])};
        *(short4*)(&Xs[(m4 + r) * PITCH + cg]) = sv;
      }
    }
    __syncthreads();
#pragma unroll
    for (int ks = 0; ks < 2; ++ks) {
      const int ko = ks * 32 + lk;
      s16x8 bfr[2];
#pragma unroll
      for (int j = 0; j < 2; ++j)
        bfr[j] = *(const s16x8*)(&Xs[(((w >> 1) * 2 + j) * 16 + lrow) * PITCH + ko]);
#pragma unroll
      for (int i = 0; i < 4; ++i) {
        const s16x8 af = *(const s16x8*)(&Aw[(((w & 1) * 4 + i) * 16 + lrow) * PITCH + ko]);
#pragma unroll
        for (int j = 0; j < 2; ++j)
          acc[i][j] = __builtin_amdgcn_mfma_f32_16x16x32_bf16(af, bfr[j], acc[i][j], 0, 0, 0);
      }
    }
  }
#pragma unroll
  for (int i = 0; i < 4; ++i) {
    const int p = p0 + ((w & 1) * 4 + i) * 16 + (lane >> 4) * 4;
#pragma unroll
    for (int j = 0; j < 2; ++j) {
      const int m = m0 + ((w >> 1) * 2 + j) * 16 + lrow;
      const f32x4 v = acc[i][j];
      short4 sv = {bf16of(v.x), bf16of(v.y), bf16of(v.z), bf16of(v.w)};
      *(short4*)(ybf + (size_t)m * 256 + p) = sv;
    }
  }
}

// ---------------------------------------------------------------------------
// K2 (fused): depthwise 3x3 (from ybf, L2-hot) -> xm row tile in LDS ->
// lower-GEMM xl = relu(xm @ lw^T + lb).  Grid (256 rows, 2 n-halves).
// by==0 block also writes xmb (for EM). One wave handles 16 px; lanes = ch.
// ---------------------------------------------------------------------------
__global__ __launch_bounds__(256) void k_dw_lower(
    const unsigned short* __restrict__ ybf, const float* __restrict__ w3,
    const float* __restrict__ b3, const float* __restrict__ lw,
    const float* __restrict__ lb, short* __restrict__ xmb,
    short* __restrict__ xlb) {
  __shared__ __align__(16) short XsF[64 * XPITCH];  // xm tile [px][k=256]
  __shared__ __align__(16) short Aw[128 * PITCH];   // lw tile [n][k-chunk]
  __shared__ float wt[9][256];
  __shared__ float bs[256];
  const int t = threadIdx.x;
  const int rt = blockIdx.x;  // row-tile = one image row
  const int n0 = blockIdx.y * 128;
  const int img = rt >> 6, h = rt & 63;
  const int m0 = rt * 64;
  const int lane = t & 63, w = t >> 6;
#pragma unroll
  for (int i = 0; i < 9; ++i) wt[i][t] = w3[t * 9 + i];
  bs[t] = b3[t];
  __syncthreads();

  // ---- phase 1: dwconv for this row; lanes = channel quads, coalesced ----
  {
    const int ch = lane * 4;
    const float4 bias = *(const float4*)(&bs[ch]);
    const size_t rowbase = ((size_t)(img << 12) + (h << 6)) * 256 + ch;
#pragma unroll 4
    for (int i = 0; i < 16; ++i) {
      const int px = w * 16 + i;
      float a0 = bias.x, a1 = bias.y, a2 = bias.z, a3 = bias.w;
#pragma unroll
      for (int dy = -1; dy <= 1; ++dy) {
        const int hh = h + dy;
        if (hh < 0 || hh > 63) continue;
#pragma unroll
        for (int dx = -1; dx <= 1; ++dx) {
          const int w2 = px + dx;
          if (w2 < 0 || w2 > 63) continue;
          const int idx = (dy + 1) * 3 + (dx + 1);
          const ushort4 v = *(const ushort4*)(
              ybf + ((size_t)(img << 12) + (hh << 6) + w2) * 256 + ch);
          const float4 wv = *(const float4*)(&wt[idx][ch]);
          a0 = fmaf(f32of(v.x), wv.x, a0);
          a1 = fmaf(f32of(v.y), wv.y, a1);
          a2 = fmaf(f32of(v.z), wv.z, a2);
          a3 = fmaf(f32of(v.w), wv.w, a3);
        }
      }
      const short4 sv = {bf16of(a0), bf16of(a1), bf16of(a2), bf16of(a3)};
      *(short4*)(&XsF[px * XPITCH + ch]) = sv;
      if (blockIdx.y == 0) *(short4*)(xmb + (size_t)(m0 + px) * 256 + ch) = sv;
    }
    (void)rowbase;
  }
  __syncthreads();

  // ---- phase 2: MFMA GEMM over K=256 (stage Aw per 64-chunk) ----
  const int lrow = lane & 15, lk = (lane >> 4) * 8;
  f32x4 acc[4][2];
#pragma unroll
  for (int i = 0; i < 4; ++i)
#pragma unroll
    for (int j = 0; j < 2; ++j) acc[i][j] = {0.f, 0.f, 0.f, 0.f};

  for (int kk = 0; kk < 256; kk += 64) {
    __syncthreads();
    {  // stage lw rows n0..n0+127
      const int nr = t & 127, kq = t >> 7;
      const float* wp = lw + (size_t)(n0 + nr) * 256 + kk + kq * 32;
#pragma unroll
      for (int q = 0; q < 8; ++q) {
        const float4 v = *(const float4*)(wp + q * 4);
        short4 sv = {bf16of(v.x), bf16of(v.y), bf16of(v.z), bf16of(v.w)};
        *(short4*)(&Aw[nr * PITCH + kq * 32 + q * 4]) = sv;
      }
    }
    __syncthreads();
#pragma unroll
    for (int ks = 0; ks < 2; ++ks) {
      const int ko = ks * 32 + lk;
      s16x8 bfr[2];
#pragma unroll
      for (int j = 0; j < 2; ++j)
        bfr[j] = *(const s16x8*)(
            &XsF[(((w >> 1) * 2 + j) * 16 + lrow) * XPITCH + kk + ko]);
#pragma unroll
      for (int i = 0; i < 4; ++i) {
        const s16x8 af = *(const s16x8*)(&Aw[(((w & 1) * 4 + i) * 16 + lrow) * PITCH + ko]);
#pragma unroll
        for (int j = 0; j < 2; ++j)
          acc[i][j] = __builtin_amdgcn_mfma_f32_16x16x32_bf16(af, bfr[j], acc[i][j], 0, 0, 0);
      }
    }
  }
#pragma unroll
  for (int i = 0; i < 4; ++i) {
    const int n = n0 + ((w & 1) * 4 + i) * 16 + (lane >> 4) * 4;
    const float4 bias = *(const float4*)(lb + n);
#pragma unroll
    for (int j = 0; j < 2; ++j) {
      const int m = m0 + ((w >> 1) * 2 + j) * 16 + lrow;
      const f32x4 v = acc[i][j];
      short4 sv = {bf16of(fmaxf(v.x + bias.x, 0.f)), bf16of(fmaxf(v.y + bias.y, 0.f)),
                   bf16of(fmaxf(v.z + bias.z, 0.f)), bf16of(fmaxf(v.w + bias.w, 0.f))};
      *(short4*)(xlb + (size_t)m * 256 + n) = sv;
    }
  }
}

// ---------------------------------------------------------------------------
// K3a: fast EM + fused pooling via device atomics (gsum add, gmax uint-max;
// feat >= 0 so float bits are monotone).
// ---------------------------------------------------------------------------
__global__ __launch_bounds__(256) void k_em_fast(const unsigned short* __restrict__ xlb,
                                                 const float* __restrict__ binit,
                                                 const unsigned short* __restrict__ xmb,
                                                 short* __restrict__ featb,
                                                 float* __restrict__ gsum,
                                                 unsigned int* __restrict__ gmaxu,
                                                 int* __restrict__ flag) {
  __shared__ float psL[1024], pmL[1024];
  __shared__ int sflag;
  const int t = threadIdx.x;
  const int lane = t & 63, w = t >> 6;
  const int bid = blockIdx.x;
  const int m0 = bid * 16 + w * 4;
  bool asym = false;
#pragma unroll
  for (int p = 0; p < 4; ++p) {
    const float bv = binit[(size_t)(m0 + p) * 16 + (lane & 15)];
    const float bn = bv / fmaxf(fabsf(bv), 1e-12f);
    asym |= !__all(bn == 1.0f);
  }
  if (t == 0) sflag = 0;
  __syncthreads();
  if (asym && lane == 0) sflag = 1;
  __syncthreads();
  if (sflag) {
    if (t == 0) flag[bid] = 1;
    return;
  }

  float s[4][4], C[4][4], Bv[4];
#pragma unroll
  for (int p = 0; p < 4; ++p) {
    const ushort4 su = *(const ushort4*)(xlb + (size_t)(m0 + p) * 256 + lane * 4);
    s[p][0] = f32of(su.x);
    s[p][1] = f32of(su.y);
    s[p][2] = f32of(su.z);
    s[p][3] = f32of(su.w);
    Bv[p] = 1.f;
#pragma unroll
    for (int i = 0; i < 4; ++i) C[p][i] = 0.0625f;
  }
  for (int step = 0; step < 6; ++step) {
    float pnum[4], psq[4];
#pragma unroll
    for (int p = 0; p < 4; ++p) {
      const float k1 = 16.f * Bv[p] * Bv[p];
      pnum[p] = 0.f;
      psq[p] = 0.f;
#pragma unroll
      for (int i = 0; i < 4; ++i) {
        const float den = fmaf(C[p][i], k1, EPS);
        const float cn = C[p][i] * (s[p][i] * Bv[p]) * __builtin_amdgcn_rcpf(den);
        C[p][i] = cn;
        pnum[p] = fmaf(s[p][i], cn, pnum[p]);
        psq[p] = fmaf(cn, cn, psq[p]);
      }
    }
#pragma unroll
    for (int d = 1; d < 64; d <<= 1) {
#pragma unroll
      for (int p = 0; p < 4; ++p) {
        pnum[p] += __shfl_xor(pnum[p], d, 64);
        psq[p] += __shfl_xor(psq[p], d, 64);
      }
    }
#pragma unroll
    for (int p = 0; p < 4; ++p)
      Bv[p] = Bv[p] * pnum[p] *
              __builtin_amdgcn_rcpf(fmaf(16.f * Bv[p], psq[p], EPS));
  }
  float ps4[4] = {0.f, 0.f, 0.f, 0.f};
  float pm4[4] = {-1e30f, -1e30f, -1e30f, -1e30f};
#pragma unroll
  for (int p = 0; p < 4; ++p) {
    const ushort4 xmu = *(const ushort4*)(xmb + (size_t)(m0 + p) * 256 + lane * 4);
    const float xmv[4] = {f32of(xmu.x), f32of(xmu.y), f32of(xmu.z), f32of(xmu.w)};
    const float k1 = 16.f * Bv[p] * Bv[p];
    float o[4];
#pragma unroll
    for (int i = 0; i < 4; ++i) {
      const float den = fmaf(C[p][i], k1, EPS);
      const float cn = C[p][i] * (s[p][i] * Bv[p]) * __builtin_amdgcn_rcpf(den);
      const float xr = 16.f * Bv[p] * cn;
      o[i] = fmaxf(xmv[i] + xr, 0.f);
      ps4[i] += o[i];
      pm4[i] = fmaxf(pm4[i], o[i]);
    }
    short4 sv = {bf16of(o[0]), bf16of(o[1]), bf16of(o[2]), bf16of(o[3])};
    *(short4*)(featb + (size_t)(m0 + p) * 256 + lane * 4) = sv;
  }
#pragma unroll
  for (int i = 0; i < 4; ++i) {
    psL[w * 256 + lane * 4 + i] = ps4[i];
    pmL[w * 256 + lane * 4 + i] = pm4[i];
  }
  __syncthreads();
  const float sv = psL[t] + psL[256 + t] + psL[512 + t] + psL[768 + t];
  const float mv =
      fmaxf(fmaxf(pmL[t], pmL[256 + t]), fmaxf(pmL[512 + t], pmL[768 + t]));
  const int img = bid >> 8;
  atomicAdd(&gsum[img * 256 + t], sv);
  atomicMax(&gmaxu[img * 256 + t], __float_as_uint(mv));
  if (t == 0) flag[bid] = 0;
}

// ---------------------------------------------------------------------------
// K3b: flag-gated general-EM recompute of a 16-pixel chunk (atomic pooling).
// ---------------------------------------------------------------------------
__global__ __launch_bounds__(256, 2) void k_em_slowfix(
    const unsigned short* __restrict__ xlb, const float* __restrict__ binit,
    const unsigned short* __restrict__ xmb, short* __restrict__ featb,
    float* __restrict__ gsum, unsigned int* __restrict__ gmaxu,
    const int* __restrict__ flag) {
  const int bid = blockIdx.x;
  if (flag[bid] == 0) return;
  __shared__ float psL[1024], pmL[1024];
  const int t = threadIdx.x;
  const int lane = t & 63, w = t >> 6;
  const int m0 = bid * 16 + w * 4;
  float ps4[4] = {0.f, 0.f, 0.f, 0.f};
  float pm4[4] = {-1e30f, -1e30f, -1e30f, -1e30f};
  for (int p = 0; p < 4; ++p) {
    const int m = m0 + p;
    const ushort4 su = *(const ushort4*)(xlb + (size_t)m * 256 + lane * 4);
    const float s[4] = {f32of(su.x), f32of(su.y), f32of(su.z), f32of(su.w)};
    float b[16];
#pragma unroll
    for (int r = 0; r < 16; ++r) {
      const float v = binit[(size_t)m * 16 + r];
      b[r] = v / fmaxf(fabsf(v), 1e-12f);
    }
    float c[4][16];
#pragma unroll
    for (int i = 0; i < 4; ++i) {
      float mx = s[i] * b[0];
#pragma unroll
      for (int r = 1; r < 16; ++r) mx = fmaxf(mx, s[i] * b[r]);
      float sum = 0.f;
#pragma unroll
      for (int r = 0; r < 16; ++r) {
        const float e = __expf(s[i] * b[r] - mx);
        c[i][r] = e;
        sum += e;
      }
      const float inv = __fdividef(1.f, sum);
#pragma unroll
      for (int r = 0; r < 16; ++r) c[i][r] *= inv;
    }
    for (int step = 0; step < 6; ++step) {
      float red[32];
#pragma unroll
      for (int r = 0; r < 32; ++r) red[r] = 0.f;
#pragma unroll
      for (int i = 0; i < 4; ++i) {
        float tt = 0.f;
#pragma unroll
        for (int r = 0; r < 16; ++r) tt += c[i][r] * b[r];
        float tp = 0.f;
#pragma unroll
        for (int r = 0; r < 16; ++r) {
          const float cn = c[i][r] * (s[i] * b[r]) * __frcp_rn(tt * b[r] + EPS);
          c[i][r] = cn;
          tp += cn * b[r];
          red[r] += s[i] * cn;
        }
#pragma unroll
        for (int r = 0; r < 16; ++r) red[16 + r] += tp * c[i][r];
      }
      int cnt = 32;
#pragma unroll
      for (int k = 4; k >= 0; --k) {
        const int d = 1 << k;
        const bool up = (lane >> k) & 1;
        const int half = cnt >> 1;
#pragma unroll
        for (int j = 0; j < half; ++j) {
          const float lo = red[j], hi = red[j + half];
          const float send = up ? lo : hi;
          const float recv = __shfl_xor(send, d, 64);
          red[j] = (up ? hi : lo) + recv;
        }
        cnt = half;
      }
      float S = red[0] + __shfl_xor(red[0], 32, 64);
      const float dpart = __shfl_xor(S, 16, 64);
      const float q = S * __frcp_rn(dpart + EPS);
#pragma unroll
      for (int r = 0; r < 16; ++r) b[r] *= __shfl(q, r, 64);
    }
    const ushort4 xmu = *(const ushort4*)(xmb + (size_t)m * 256 + lane * 4);
    const float xmv[4] = {f32of(xmu.x), f32of(xmu.y), f32of(xmu.z), f32of(xmu.w)};
    float o4[4];
#pragma unroll
    for (int i = 0; i < 4; ++i) {
      float tt = 0.f;
#pragma unroll
      for (int r = 0; r < 16; ++r) tt += c[i][r] * b[r];
      float xr = 0.f;
#pragma unroll
      for (int r = 0; r < 16; ++r) {
        const float cn = c[i][r] * (s[i] * b[r]) * __frcp_rn(tt * b[r] + EPS);
        xr += b[r] * cn;
      }
      o4[i] = fmaxf(xmv[i] + xr, 0.f);
      ps4[i] += o4[i];
      pm4[i] = fmaxf(pm4[i], o4[i]);
    }
    short4 sv = {bf16of(o4[0]), bf16of(o4[1]), bf16of(o4[2]), bf16of(o4[3])};
    *(short4*)(featb + (size_t)m * 256 + lane * 4) = sv;
  }
#pragma unroll
  for (int i = 0; i < 4; ++i) {
    psL[w * 256 + lane * 4 + i] = ps4[i];
    pmL[w * 256 + lane * 4 + i] = pm4[i];
  }
  __syncthreads();
  const float sv = psL[t] + psL[256 + t] + psL[512 + t] + psL[768 + t];
  const float mv =
      fmaxf(fmaxf(pmL[t], pmL[256 + t]), fmaxf(pmL[512 + t], pmL[768 + t]));
  const int img = bid >> 8;
  atomicAdd(&gsum[img * 256 + t], sv);
  atomicMax(&gmaxu[img * 256 + t], __float_as_uint(mv));
}

// ---------------------------------------------------------------------------
// K4: channel-attention MLP + sigmoid from the 4 KB accumulators.
// ---------------------------------------------------------------------------
__global__ __launch_bounds__(256) void k_att(const float* __restrict__ gsum,
                                             const unsigned int* __restrict__ gmaxu,
                                             const float* __restrict__ ca1,
                                             const float* __restrict__ ca2,
                                             float* __restrict__ attv,
                                             float* __restrict__ out_att) {
  __shared__ float fA[256], fM[256], sH[64];
  const int t = threadIdx.x;
  const int b = blockIdx.x;
  fA[t] = gsum[b * 256 + t] * (1.0f / 4096.0f);
  fM[t] = __uint_as_float(gmaxu[b * 256 + t]);
  __syncthreads();
  if (t < 64) {
    float ha = 0.f, hm = 0.f;
#pragma unroll 8
    for (int p = 0; p < 256; ++p) {
      const float wv = ca1[t * 256 + p];
      ha += fA[p] * wv;
      hm += fM[p] * wv;
    }
    sH[t] = fmaxf(ha, 0.f) + fmaxf(hm, 0.f);
  }
  __syncthreads();
  float logit = 0.f;
#pragma unroll 8
  for (int a = 0; a < 64; ++a) logit += sH[a] * ca2[t * 64 + a];
  const float av = 1.0f / (1.0f + expf(-logit));
  attv[b * 256 + t] = av;
  out_att[b * 256 + t] = av;
}

// ---------------------------------------------------------------------------
// K5 (MFMA): out = (feat*att) @ fw^T + fb.  64m x 64o per block, grid (256,2).
// ---------------------------------------------------------------------------
__global__ __launch_bounds__(256) void k_fc(const unsigned short* __restrict__ featb,
                                            const float* __restrict__ attv,
                                            const float* __restrict__ fw,
                                            const float* __restrict__ fb,
                                            float* __restrict__ out) {
  __shared__ __align__(16) short Fs[64 * PITCH];  // [m][k]
  __shared__ __align__(16) short Ws[64 * PITCH];  // [o][k]
  const int t = threadIdx.x;
  const int m0 = blockIdx.x * 64, o0 = blockIdx.y * 64;
  const int img = m0 >> 12, hw0 = m0 & 4095;
  const int lane = t & 63, w = t >> 6;
  const int lrow = lane & 15, lk = (lane >> 4) * 8;
  f32x4 acc[2][2];
#pragma unroll
  for (int i = 0; i < 2; ++i)
#pragma unroll
    for (int j = 0; j < 2; ++j) acc[i][j] = {0.f, 0.f, 0.f, 0.f};

  for (int kk = 0; kk < 256; kk += 64) {
    __syncthreads();
    {  // stage feat * att
      const int m = t & 63, q = t >> 6;
      const unsigned short* fp = featb + (size_t)(m0 + m) * 256 + kk + q * 16;
      const float* ap = attv + img * 256 + kk + q * 16;
#pragma unroll
      for (int jj = 0; jj < 4; ++jj) {
        const ushort4 v = *(const ushort4*)(fp + jj * 4);
        const float4 a = *(const float4*)(ap + jj * 4);
        short4 sv = {bf16of(f32of(v.x) * a.x), bf16of(f32of(v.y) * a.y),
                     bf16of(f32of(v.z) * a.z), bf16of(f32of(v.w) * a.w)};
        *(short4*)(&Fs[m * PITCH + q * 16 + jj * 4]) = sv;
      }
    }
    {  // stage fw rows o0..o0+63
      const int o = t & 63, q = t >> 6;
      const float* wp = fw + (size_t)(o0 + o) * 256 + kk + q * 16;
#pragma unroll
      for (int jj = 0; jj < 4; ++jj) {
        const float4 v = *(const float4*)(wp + jj * 4);
        short4 sv = {bf16of(v.x), bf16of(v.y), bf16of(v.z), bf16of(v.w)};
        *(short4*)(&Ws[o * PITCH + q * 16 + jj * 4]) = sv;
      }
    }
    __syncthreads();
#pragma unroll
    for (int ks = 0; ks < 2; ++ks) {
      const int ko = ks * 32 + lk;
      s16x8 af[2];
#pragma unroll
      for (int i = 0; i < 2; ++i)
        af[i] = *(const s16x8*)(&Fs[(((w >> 1) * 2 + i) * 16 + lrow) * PITCH + ko]);
#pragma unroll
      for (int j = 0; j < 2; ++j) {
        const s16x8 bfr = *(const s16x8*)(&Ws[(((w & 1) * 2 + j) * 16 + lrow) * PITCH + ko]);
#pragma unroll
        for (int i = 0; i < 2; ++i)
          acc[i][j] = __builtin_amdgcn_mfma_f32_16x16x32_bf16(af[i], bfr, acc[i][j], 0, 0, 0);
      }
    }
  }
#pragma unroll
  for (int j = 0; j < 2; ++j) {
    const int o = o0 + ((w & 1) * 2 + j) * 16 + lrow;
    const float bias = fb[o];
#pragma unroll
    for (int i = 0; i < 2; ++i) {
      const int hw = hw0 + ((w >> 1) * 2 + i) * 16 + (lane >> 4) * 4;
      f32x4 v = acc[i][j];
      v.x += bias;
      v.y += bias;
      v.z += bias;
      v.w += bias;
      *(f32x4*)(out + (size_t)img * 524288 + (size_t)o * 4096 + hw) = v;
    }
  }
}

extern "C" void kernel_launch(void* const* d_in, const int* in_sizes, int n_in,
                              void* d_out, int out_size, void* d_ws, size_t ws_size,
                              hipStream_t stream) {
  const float* x = (const float*)d_in[0];
  const float* w1 = (const float*)d_in[1];
  const float* w3 = (const float*)d_in[2];
  const float* b3 = (const float*)d_in[3];
  const float* lw = (const float*)d_in[4];
  const float* lb = (const float*)d_in[5];
  const float* ca1 = (const float*)d_in[6];
  const float* ca2 = (const float*)d_in[7];
  const float* fw = (const float*)d_in[8];
  const float* fb = (const float*)d_in[9];
  const float* binit = (const float*)d_in[10];

  char* wsb = (char*)d_ws;
  short* ybf = (short*)wsb;                        // 8 MB bf16
  short* xmb = (short*)(wsb + (8u << 20));         // 8 MB bf16
  short* xlb = (short*)(wsb + (16u << 20));        // 8 MB bf16
  short* featb = (short*)(wsb + (24u << 20));      // 8 MB bf16
  float* gsum = (float*)(wsb + (32u << 20));       // 4 KB
  unsigned int* gmaxu = (unsigned int*)(wsb + (33u << 20));  // 4 KB
  float* attv = (float*)(wsb + (34u << 20));       // 4 KB
  int* flag = (int*)(wsb + (35u << 20));           // 4 KB
  float* out = (float*)d_out;
  float* out_att = out + 2097152;

  const dim3 blk(256);
  k_conv1x1<<<dim3(256, 2), blk, 0, stream>>>(x, w1, ybf, gsum, gmaxu);
  k_dw_lower<<<dim3(256, 2), blk, 0, stream>>>((const unsigned short*)ybf, w3, b3,
                                               lw, lb, xmb, xlb);
  k_em_fast<<<dim3(1024), blk, 0, stream>>>((const unsigned short*)xlb, binit,
                                            (const unsigned short*)xmb, featb,
                                            gsum, gmaxu, flag);
  k_em_slowfix<<<dim3(1024), blk, 0, stream>>>((const unsigned short*)xlb, binit,
                                               (const unsigned short*)xmb, featb,
                                               gsum, gmaxu, flag);
  k_att<<<dim3(4), blk, 0, stream>>>(gsum, gmaxu, ca1, ca2, attv, out_att);
  k_fc<<<dim3(256, 2), blk, 0, stream>>>((const unsigned short*)featb, attv, fw,
                                         fb, out);
}

// Round 10
// 87.516 us; speedup vs baseline: 1.2713x; 1.2713x over previous
//
#include <hip/hip_runtime.h>
#include <hip/hip_bf16.h>
#include <math.h>

#define EPS 1e-6f
#define PITCH 72  // bf16 elems per LDS row: 64 K + 8 pad (2-way bank conflict = free)

typedef short s16x8 __attribute__((ext_vector_type(8)));
typedef float f32x4 __attribute__((ext_vector_type(4)));

__device__ __forceinline__ short bf16of(float f) {
  __hip_bfloat16 h = __float2bfloat16(f);
  return __builtin_bit_cast(short, h);
}
__device__ __forceinline__ float f32of(unsigned short u) {
  unsigned int x = ((unsigned int)u) << 16;
  return __builtin_bit_cast(float, x);
}

// ---------------------------------------------------------------------------
// K1 (MFMA): y[m][p] = sum_c x[img][c][hw] * w1[p][c].  Output bf16.
// 64m x 128p per block, grid (256, 2) = 2 blocks/CU.
// Block (0,0) zero-inits pooling accumulators (stream-ordered before em).
// ---------------------------------------------------------------------------
__global__ __launch_bounds__(256) void k_conv1x1(const float* __restrict__ x,
                                                 const float* __restrict__ w1,
                                                 short* __restrict__ ybf,
                                                 float* __restrict__ gsum,
                                                 unsigned int* __restrict__ gmaxu) {
  __shared__ __align__(16) short Aw[128 * PITCH];  // [p][k]
  __shared__ __align__(16) short Xs[64 * PITCH];   // [m][k]
  const int t = threadIdx.x;
  if (blockIdx.x == 0 && blockIdx.y == 0) {
#pragma unroll
    for (int i = 0; i < 4; ++i) {
      gsum[t + i * 256] = 0.f;
      gmaxu[t + i * 256] = 0u;
    }
  }
  const int m0 = blockIdx.x * 64, p0 = blockIdx.y * 128;
  const int img = m0 >> 12, hw0 = m0 & 4095;
  const int lane = t & 63, w = t >> 6;
  const int lrow = lane & 15, lk = (lane >> 4) * 8;
  f32x4 acc[4][2];
#pragma unroll
  for (int i = 0; i < 4; ++i)
#pragma unroll
    for (int j = 0; j < 2; ++j) acc[i][j] = {0.f, 0.f, 0.f, 0.f};

  for (int kk = 0; kk < 128; kk += 64) {
    __syncthreads();
    {  // stage w1 rows p0..p0+127, 32 k-elems per thread
      const int pr = t & 127, kq = t >> 7;
      const float* wp = w1 + (size_t)(p0 + pr) * 128 + kk + kq * 32;
#pragma unroll
      for (int q = 0; q < 8; ++q) {
        const float4 v = *(const float4*)(wp + q * 4);
        short4 sv = {bf16of(v.x), bf16of(v.y), bf16of(v.z), bf16of(v.w)};
        *(short4*)(&Aw[pr * PITCH + kq * 32 + q * 4]) = sv;
      }
    }
    {  // stage x (c-major) -> Xs[m][c]: 4x4 register transpose
      const int m4 = (t & 15) * 4;
      const int cg = (t >> 4) * 4;
      float4 col[4];
#pragma unroll
      for (int cc = 0; cc < 4; ++cc)
        col[cc] = *(const float4*)(x + (size_t)(img * 128 + kk + cg + cc) * 4096 + hw0 + m4);
#pragma unroll
      for (int r = 0; r < 4; ++r) {
        short4 sv = {bf16of(((const float*)&col[0])[r]),
                     bf16of(((const float*)&col[1])[r]),
                     bf16of(((const float*)&col[2])[r]),
                     bf16of(((const float*)&col[3])[r])};
        *(short4*)(&Xs[(m4 + r) * PITCH + cg]) = sv;
      }
    }
    __syncthreads();
#pragma unroll
    for (int ks = 0; ks < 2; ++ks) {
      const int ko = ks * 32 + lk;
      s16x8 bfr[2];
#pragma unroll
      for (int j = 0; j < 2; ++j)
        bfr[j] = *(const s16x8*)(&Xs[(((w >> 1) * 2 + j) * 16 + lrow) * PITCH + ko]);
#pragma unroll
      for (int i = 0; i < 4; ++i) {
        const s16x8 af = *(const s16x8*)(&Aw[(((w & 1) * 4 + i) * 16 + lrow) * PITCH + ko]);
#pragma unroll
        for (int j = 0; j < 2; ++j)
          acc[i][j] = __builtin_amdgcn_mfma_f32_16x16x32_bf16(af, bfr[j], acc[i][j], 0, 0, 0);
      }
    }
  }
#pragma unroll
  for (int i = 0; i < 4; ++i) {
    const int p = p0 + ((w & 1) * 4 + i) * 16 + (lane >> 4) * 4;
#pragma unroll
    for (int j = 0; j < 2; ++j) {
      const int m = m0 + ((w >> 1) * 2 + j) * 16 + lrow;
      const f32x4 v = acc[i][j];
      short4 sv = {bf16of(v.x), bf16of(v.y), bf16of(v.z), bf16of(v.w)};
      *(short4*)(ybf + (size_t)m * 256 + p) = sv;
    }
  }
}

// ---------------------------------------------------------------------------
// K2: depthwise 3x3 SAME + bias; bf16 in, bf16 out (round-8 validated).
// ---------------------------------------------------------------------------
__global__ __launch_bounds__(256) void k_dwconv(const unsigned short* __restrict__ ybf,
                                                const float* __restrict__ w3,
                                                const float* __restrict__ b3,
                                                short* __restrict__ xmb) {
  __shared__ float wt[9][256];
  __shared__ float bs[256];
  const int t = threadIdx.x;
#pragma unroll
  for (int i = 0; i < 9; ++i) wt[i][t] = w3[t * 9 + i];
  bs[t] = b3[t];
  __syncthreads();
  const int sub = t >> 6;
  const int pq = t & 63;
  const int m = blockIdx.x * 4 + sub;
  const int hw = m & 4095;
  const int h = hw >> 6, ww = hw & 63;
  const int bb = m >> 12;
  float4 acc = *(const float4*)(&bs[pq * 4]);
#pragma unroll
  for (int dy = -1; dy <= 1; ++dy) {
    const int hh = h + dy;
    if (hh < 0 || hh > 63) continue;
#pragma unroll
    for (int dx = -1; dx <= 1; ++dx) {
      const int w2 = ww + dx;
      if (w2 < 0 || w2 > 63) continue;
      const int idx = (dy + 1) * 3 + (dx + 1);
      const ushort4 v =
          *(const ushort4*)(ybf + (size_t)((bb << 12) + (hh << 6) + w2) * 256 + pq * 4);
      const float4 wv = *(const float4*)(&wt[idx][pq * 4]);
      acc.x += f32of(v.x) * wv.x;
      acc.y += f32of(v.y) * wv.y;
      acc.z += f32of(v.z) * wv.z;
      acc.w += f32of(v.w) * wv.w;
    }
  }
  short4 sv = {bf16of(acc.x), bf16of(acc.y), bf16of(acc.z), bf16of(acc.w)};
  *(short4*)(xmb + (size_t)m * 256 + pq * 4) = sv;
}

// ---------------------------------------------------------------------------
// K3 (MFMA): xl = relu(xm @ lw^T + lb).  64m x 128n, grid (256, 2).
// ---------------------------------------------------------------------------
__global__ __launch_bounds__(256) void k_lower(const unsigned short* __restrict__ xmb,
                                               const float* __restrict__ lw,
                                               const float* __restrict__ lb,
                                               short* __restrict__ xlb) {
  __shared__ __align__(16) short Aw[128 * PITCH];  // [n][k]
  __shared__ __align__(16) short Xs[64 * PITCH];   // [m][k]
  const int t = threadIdx.x;
  const int m0 = blockIdx.x * 64, n0 = blockIdx.y * 128;
  const int lane = t & 63, w = t >> 6;
  const int lrow = lane & 15, lk = (lane >> 4) * 8;
  f32x4 acc[4][2];
#pragma unroll
  for (int i = 0; i < 4; ++i)
#pragma unroll
    for (int j = 0; j < 2; ++j) acc[i][j] = {0.f, 0.f, 0.f, 0.f};

  for (int kk = 0; kk < 256; kk += 64) {
    __syncthreads();
    {  // stage lw rows n0..n0+127
      const int nr = t & 127, kq = t >> 7;
      const float* wp = lw + (size_t)(n0 + nr) * 256 + kk + kq * 32;
#pragma unroll
      for (int q = 0; q < 8; ++q) {
        const float4 v = *(const float4*)(wp + q * 4);
        short4 sv = {bf16of(v.x), bf16of(v.y), bf16of(v.z), bf16of(v.w)};
        *(short4*)(&Aw[nr * PITCH + kq * 32 + q * 4]) = sv;
      }
    }
    {  // stage xm (already bf16) — straight copy
      const int m = t & 63, q = t >> 6;
      const unsigned short* xp = xmb + (size_t)(m0 + m) * 256 + kk + q * 16;
      *(s16x8*)(&Xs[m * PITCH + q * 16]) = *(const s16x8*)(xp);
      *(s16x8*)(&Xs[m * PITCH + q * 16 + 8]) = *(const s16x8*)(xp + 8);
    }
    __syncthreads();
#pragma unroll
    for (int ks = 0; ks < 2; ++ks) {
      const int ko = ks * 32 + lk;
      s16x8 bfr[2];
#pragma unroll
      for (int j = 0; j < 2; ++j)
        bfr[j] = *(const s16x8*)(&Xs[(((w >> 1) * 2 + j) * 16 + lrow) * PITCH + ko]);
#pragma unroll
      for (int i = 0; i < 4; ++i) {
        const s16x8 af = *(const s16x8*)(&Aw[(((w & 1) * 4 + i) * 16 + lrow) * PITCH + ko]);
#pragma unroll
        for (int j = 0; j < 2; ++j)
          acc[i][j] = __builtin_amdgcn_mfma_f32_16x16x32_bf16(af, bfr[j], acc[i][j], 0, 0, 0);
      }
    }
  }
#pragma unroll
  for (int i = 0; i < 4; ++i) {
    const int n = n0 + ((w & 1) * 4 + i) * 16 + (lane >> 4) * 4;
    const float4 bias = *(const float4*)(lb + n);
#pragma unroll
    for (int j = 0; j < 2; ++j) {
      const int m = m0 + ((w >> 1) * 2 + j) * 16 + lrow;
      const f32x4 v = acc[i][j];
      short4 sv = {bf16of(fmaxf(v.x + bias.x, 0.f)), bf16of(fmaxf(v.y + bias.y, 0.f)),
                   bf16of(fmaxf(v.z + bias.z, 0.f)), bf16of(fmaxf(v.w + bias.w, 0.f))};
      *(short4*)(xlb + (size_t)m * 256 + n) = sv;
    }
  }
}

// ---------------------------------------------------------------------------
// K4a: fast EM (ILP-4) + pooling via device atomics (gsum add, gmaxu
// uint-max; feat >= 0 so float bits are monotone).
// ---------------------------------------------------------------------------
__global__ __launch_bounds__(256) void k_em_fast(const unsigned short* __restrict__ xlb,
                                                 const float* __restrict__ binit,
                                                 const unsigned short* __restrict__ xmb,
                                                 short* __restrict__ featb,
                                                 float* __restrict__ gsum,
                                                 unsigned int* __restrict__ gmaxu,
                                                 int* __restrict__ flag) {
  __shared__ float psL[1024], pmL[1024];
  __shared__ int sflag;
  const int t = threadIdx.x;
  const int lane = t & 63, w = t >> 6;
  const int bid = blockIdx.x;
  const int m0 = bid * 16 + w * 4;
  bool asym = false;
#pragma unroll
  for (int p = 0; p < 4; ++p) {
    const float bv = binit[(size_t)(m0 + p) * 16 + (lane & 15)];
    const float bn = bv / fmaxf(fabsf(bv), 1e-12f);
    asym |= !__all(bn == 1.0f);
  }
  if (t == 0) sflag = 0;
  __syncthreads();
  if (asym && lane == 0) sflag = 1;
  __syncthreads();
  if (sflag) {
    if (t == 0) flag[bid] = 1;
    return;
  }

  float s[4][4], C[4][4], Bv[4];
#pragma unroll
  for (int p = 0; p < 4; ++p) {
    const ushort4 su = *(const ushort4*)(xlb + (size_t)(m0 + p) * 256 + lane * 4);
    s[p][0] = f32of(su.x);
    s[p][1] = f32of(su.y);
    s[p][2] = f32of(su.z);
    s[p][3] = f32of(su.w);
    Bv[p] = 1.f;
#pragma unroll
    for (int i = 0; i < 4; ++i) C[p][i] = 0.0625f;
  }
  for (int step = 0; step < 6; ++step) {
    float pnum[4], psq[4];
#pragma unroll
    for (int p = 0; p < 4; ++p) {
      const float k1 = 16.f * Bv[p] * Bv[p];
      pnum[p] = 0.f;
      psq[p] = 0.f;
#pragma unroll
      for (int i = 0; i < 4; ++i) {
        const float den = fmaf(C[p][i], k1, EPS);
        const float cn = C[p][i] * (s[p][i] * Bv[p]) * __builtin_amdgcn_rcpf(den);
        C[p][i] = cn;
        pnum[p] = fmaf(s[p][i], cn, pnum[p]);
        psq[p] = fmaf(cn, cn, psq[p]);
      }
    }
#pragma unroll
    for (int d = 1; d < 64; d <<= 1) {
#pragma unroll
      for (int p = 0; p < 4; ++p) {
        pnum[p] += __shfl_xor(pnum[p], d, 64);
        psq[p] += __shfl_xor(psq[p], d, 64);
      }
    }
#pragma unroll
    for (int p = 0; p < 4; ++p)
      Bv[p] = Bv[p] * pnum[p] *
              __builtin_amdgcn_rcpf(fmaf(16.f * Bv[p], psq[p], EPS));
  }
  float ps4[4] = {0.f, 0.f, 0.f, 0.f};
  float pm4[4] = {-1e30f, -1e30f, -1e30f, -1e30f};
#pragma unroll
  for (int p = 0; p < 4; ++p) {
    const ushort4 xmu = *(const ushort4*)(xmb + (size_t)(m0 + p) * 256 + lane * 4);
    const float xmv[4] = {f32of(xmu.x), f32of(xmu.y), f32of(xmu.z), f32of(xmu.w)};
    const float k1 = 16.f * Bv[p] * Bv[p];
    float o[4];
#pragma unroll
    for (int i = 0; i < 4; ++i) {
      const float den = fmaf(C[p][i], k1, EPS);
      const float cn = C[p][i] * (s[p][i] * Bv[p]) * __builtin_amdgcn_rcpf(den);
      const float xr = 16.f * Bv[p] * cn;
      o[i] = fmaxf(xmv[i] + xr, 0.f);
      ps4[i] += o[i];
      pm4[i] = fmaxf(pm4[i], o[i]);
    }
    short4 sv = {bf16of(o[0]), bf16of(o[1]), bf16of(o[2]), bf16of(o[3])};
    *(short4*)(featb + (size_t)(m0 + p) * 256 + lane * 4) = sv;
  }
#pragma unroll
  for (int i = 0; i < 4; ++i) {
    psL[w * 256 + lane * 4 + i] = ps4[i];
    pmL[w * 256 + lane * 4 + i] = pm4[i];
  }
  __syncthreads();
  const float sv = psL[t] + psL[256 + t] + psL[512 + t] + psL[768 + t];
  const float mv =
      fmaxf(fmaxf(pmL[t], pmL[256 + t]), fmaxf(pmL[512 + t], pmL[768 + t]));
  const int img = bid >> 8;
  atomicAdd(&gsum[img * 256 + t], sv);
  atomicMax(&gmaxu[img * 256 + t], __float_as_uint(mv));
  if (t == 0) flag[bid] = 0;
}

// ---------------------------------------------------------------------------
// K4b: flag-gated general-EM recompute of a 16-pixel chunk (atomic pooling).
// ---------------------------------------------------------------------------
__global__ __launch_bounds__(256, 2) void k_em_slowfix(
    const unsigned short* __restrict__ xlb, const float* __restrict__ binit,
    const unsigned short* __restrict__ xmb, short* __restrict__ featb,
    float* __restrict__ gsum, unsigned int* __restrict__ gmaxu,
    const int* __restrict__ flag) {
  const int bid = blockIdx.x;
  if (flag[bid] == 0) return;
  __shared__ float psL[1024], pmL[1024];
  const int t = threadIdx.x;
  const int lane = t & 63, w = t >> 6;
  const int m0 = bid * 16 + w * 4;
  float ps4[4] = {0.f, 0.f, 0.f, 0.f};
  float pm4[4] = {-1e30f, -1e30f, -1e30f, -1e30f};
  for (int p = 0; p < 4; ++p) {
    const int m = m0 + p;
    const ushort4 su = *(const ushort4*)(xlb + (size_t)m * 256 + lane * 4);
    const float s[4] = {f32of(su.x), f32of(su.y), f32of(su.z), f32of(su.w)};
    float b[16];
#pragma unroll
    for (int r = 0; r < 16; ++r) {
      const float v = binit[(size_t)m * 16 + r];
      b[r] = v / fmaxf(fabsf(v), 1e-12f);
    }
    float c[4][16];
#pragma unroll
    for (int i = 0; i < 4; ++i) {
      float mx = s[i] * b[0];
#pragma unroll
      for (int r = 1; r < 16; ++r) mx = fmaxf(mx, s[i] * b[r]);
      float sum = 0.f;
#pragma unroll
      for (int r = 0; r < 16; ++r) {
        const float e = __expf(s[i] * b[r] - mx);
        c[i][r] = e;
        sum += e;
      }
      const float inv = __fdividef(1.f, sum);
#pragma unroll
      for (int r = 0; r < 16; ++r) c[i][r] *= inv;
    }
    for (int step = 0; step < 6; ++step) {
      float red[32];
#pragma unroll
      for (int r = 0; r < 32; ++r) red[r] = 0.f;
#pragma unroll
      for (int i = 0; i < 4; ++i) {
        float tt = 0.f;
#pragma unroll
        for (int r = 0; r < 16; ++r) tt += c[i][r] * b[r];
        float tp = 0.f;
#pragma unroll
        for (int r = 0; r < 16; ++r) {
          const float cn = c[i][r] * (s[i] * b[r]) * __frcp_rn(tt * b[r] + EPS);
          c[i][r] = cn;
          tp += cn * b[r];
          red[r] += s[i] * cn;
        }
#pragma unroll
        for (int r = 0; r < 16; ++r) red[16 + r] += tp * c[i][r];
      }
      int cnt = 32;
#pragma unroll
      for (int k = 4; k >= 0; --k) {
        const int d = 1 << k;
        const bool up = (lane >> k) & 1;
        const int half = cnt >> 1;
#pragma unroll
        for (int j = 0; j < half; ++j) {
          const float lo = red[j], hi = red[j + half];
          const float send = up ? lo : hi;
          const float recv = __shfl_xor(send, d, 64);
          red[j] = (up ? hi : lo) + recv;
        }
        cnt = half;
      }
      float S = red[0] + __shfl_xor(red[0], 32, 64);
      const float dpart = __shfl_xor(S, 16, 64);
      const float q = S * __frcp_rn(dpart + EPS);
#pragma unroll
      for (int r = 0; r < 16; ++r) b[r] *= __shfl(q, r, 64);
    }
    const ushort4 xmu = *(const ushort4*)(xmb + (size_t)m * 256 + lane * 4);
    const float xmv[4] = {f32of(xmu.x), f32of(xmu.y), f32of(xmu.z), f32of(xmu.w)};
    float o4[4];
#pragma unroll
    for (int i = 0; i < 4; ++i) {
      float tt = 0.f;
#pragma unroll
      for (int r = 0; r < 16; ++r) tt += c[i][r] * b[r];
      float xr = 0.f;
#pragma unroll
      for (int r = 0; r < 16; ++r) {
        const float cn = c[i][r] * (s[i] * b[r]) * __frcp_rn(tt * b[r] + EPS);
        xr += b[r] * cn;
      }
      o4[i] = fmaxf(xmv[i] + xr, 0.f);
      ps4[i] += o4[i];
      pm4[i] = fmaxf(pm4[i], o4[i]);
    }
    short4 sv = {bf16of(o4[0]), bf16of(o4[1]), bf16of(o4[2]), bf16of(o4[3])};
    *(short4*)(featb + (size_t)m * 256 + lane * 4) = sv;
  }
#pragma unroll
  for (int i = 0; i < 4; ++i) {
    psL[w * 256 + lane * 4 + i] = ps4[i];
    pmL[w * 256 + lane * 4 + i] = pm4[i];
  }
  __syncthreads();
  const float sv = psL[t] + psL[256 + t] + psL[512 + t] + psL[768 + t];
  const float mv =
      fmaxf(fmaxf(pmL[t], pmL[256 + t]), fmaxf(pmL[512 + t], pmL[768 + t]));
  const int img = bid >> 8;
  atomicAdd(&gsum[img * 256 + t], sv);
  atomicMax(&gmaxu[img * 256 + t], __float_as_uint(mv));
}

// ---------------------------------------------------------------------------
// K5: channel-attention MLP + sigmoid from the 4 KB accumulators.
// ---------------------------------------------------------------------------
__global__ __launch_bounds__(256) void k_att(const float* __restrict__ gsum,
                                             const unsigned int* __restrict__ gmaxu,
                                             const float* __restrict__ ca1,
                                             const float* __restrict__ ca2,
                                             float* __restrict__ attv,
                                             float* __restrict__ out_att) {
  __shared__ float fA[256], fM[256], sH[64];
  const int t = threadIdx.x;
  const int b = blockIdx.x;
  fA[t] = gsum[b * 256 + t] * (1.0f / 4096.0f);
  fM[t] = __uint_as_float(gmaxu[b * 256 + t]);
  __syncthreads();
  if (t < 64) {
    float ha = 0.f, hm = 0.f;
#pragma unroll 8
    for (int p = 0; p < 256; ++p) {
      const float wv = ca1[t * 256 + p];
      ha += fA[p] * wv;
      hm += fM[p] * wv;
    }
    sH[t] = fmaxf(ha, 0.f) + fmaxf(hm, 0.f);
  }
  __syncthreads();
  float logit = 0.f;
#pragma unroll 8
  for (int a = 0; a < 64; ++a) logit += sH[a] * ca2[t * 64 + a];
  const float av = 1.0f / (1.0f + expf(-logit));
  attv[b * 256 + t] = av;
  out_att[b * 256 + t] = av;
}

// ---------------------------------------------------------------------------
// K6 (MFMA): out = (feat*att) @ fw^T + fb.  64m x 64o, grid (256, 2).
// ---------------------------------------------------------------------------
__global__ __launch_bounds__(256) void k_fc(const unsigned short* __restrict__ featb,
                                            const float* __restrict__ attv,
                                            const float* __restrict__ fw,
                                            const float* __restrict__ fb,
                                            float* __restrict__ out) {
  __shared__ __align__(16) short Fs[64 * PITCH];  // [m][k]
  __shared__ __align__(16) short Ws[64 * PITCH];  // [o][k]
  const int t = threadIdx.x;
  const int m0 = blockIdx.x * 64, o0 = blockIdx.y * 64;
  const int img = m0 >> 12, hw0 = m0 & 4095;
  const int lane = t & 63, w = t >> 6;
  const int lrow = lane & 15, lk = (lane >> 4) * 8;
  f32x4 acc[2][2];
#pragma unroll
  for (int i = 0; i < 2; ++i)
#pragma unroll
    for (int j = 0; j < 2; ++j) acc[i][j] = {0.f, 0.f, 0.f, 0.f};

  for (int kk = 0; kk < 256; kk += 64) {
    __syncthreads();
    {  // stage feat * att
      const int m = t & 63, q = t >> 6;
      const unsigned short* fp = featb + (size_t)(m0 + m) * 256 + kk + q * 16;
      const float* ap = attv + img * 256 + kk + q * 16;
#pragma unroll
      for (int jj = 0; jj < 4; ++jj) {
        const ushort4 v = *(const ushort4*)(fp + jj * 4);
        const float4 a = *(const float4*)(ap + jj * 4);
        short4 sv = {bf16of(f32of(v.x) * a.x), bf16of(f32of(v.y) * a.y),
                     bf16of(f32of(v.z) * a.z), bf16of(f32of(v.w) * a.w)};
        *(short4*)(&Fs[m * PITCH + q * 16 + jj * 4]) = sv;
      }
    }
    {  // stage fw rows o0..o0+63
      const int o = t & 63, q = t >> 6;
      const float* wp = fw + (size_t)(o0 + o) * 256 + kk + q * 16;
#pragma unroll
      for (int jj = 0; jj < 4; ++jj) {
        const float4 v = *(const float4*)(wp + jj * 4);
        short4 sv = {bf16of(v.x), bf16of(v.y), bf16of(v.z), bf16of(v.w)};
        *(short4*)(&Ws[o * PITCH + q * 16 + jj * 4]) = sv;
      }
    }
    __syncthreads();
#pragma unroll
    for (int ks = 0; ks < 2; ++ks) {
      const int ko = ks * 32 + lk;
      s16x8 af[2];
#pragma unroll
      for (int i = 0; i < 2; ++i)
        af[i] = *(const s16x8*)(&Fs[(((w >> 1) * 2 + i) * 16 + lrow) * PITCH + ko]);
#pragma unroll
      for (int j = 0; j < 2; ++j) {
        const s16x8 bfr = *(const s16x8*)(&Ws[(((w & 1) * 2 + j) * 16 + lrow) * PITCH + ko]);
#pragma unroll
        for (int i = 0; i < 2; ++i)
          acc[i][j] = __builtin_amdgcn_mfma_f32_16x16x32_bf16(af[i], bfr, acc[i][j], 0, 0, 0);
      }
    }
  }
#pragma unroll
  for (int j = 0; j < 2; ++j) {
    const int o = o0 + ((w & 1) * 2 + j) * 16 + lrow;
    const float bias = fb[o];
#pragma unroll
    for (int i = 0; i < 2; ++i) {
      const int hw = hw0 + ((w >> 1) * 2 + i) * 16 + (lane >> 4) * 4;
      f32x4 v = acc[i][j];
      v.x += bias;
      v.y += bias;
      v.z += bias;
      v.w += bias;
      *(f32x4*)(out + (size_t)img * 524288 + (size_t)o * 4096 + hw) = v;
    }
  }
}

extern "C" void kernel_launch(void* const* d_in, const int* in_sizes, int n_in,
                              void* d_out, int out_size, void* d_ws, size_t ws_size,
                              hipStream_t stream) {
  const float* x = (const float*)d_in[0];
  const float* w1 = (const float*)d_in[1];
  const float* w3 = (const float*)d_in[2];
  const float* b3 = (const float*)d_in[3];
  const float* lw = (const float*)d_in[4];
  const float* lb = (const float*)d_in[5];
  const float* ca1 = (const float*)d_in[6];
  const float* ca2 = (const float*)d_in[7];
  const float* fw = (const float*)d_in[8];
  const float* fb = (const float*)d_in[9];
  const float* binit = (const float*)d_in[10];

  char* wsb = (char*)d_ws;
  short* ybf = (short*)wsb;                        // 8 MB bf16
  short* xmb = (short*)(wsb + (8u << 20));         // 8 MB bf16
  short* xlb = (short*)(wsb + (16u << 20));        // 8 MB bf16
  short* featb = (short*)(wsb + (24u << 20));      // 8 MB bf16
  float* gsum = (float*)(wsb + (32u << 20));       // 4 KB
  unsigned int* gmaxu = (unsigned int*)(wsb + (33u << 20));  // 4 KB
  float* attv = (float*)(wsb + (34u << 20));       // 4 KB
  int* flag = (int*)(wsb + (35u << 20));           // 4 KB
  float* out = (float*)d_out;
  float* out_att = out + 2097152;

  const dim3 blk(256);
  k_conv1x1<<<dim3(256, 2), blk, 0, stream>>>(x, w1, ybf, gsum, gmaxu);
  k_dwconv<<<dim3(4096), blk, 0, stream>>>((const unsigned short*)ybf, w3, b3, xmb);
  k_lower<<<dim3(256, 2), blk, 0, stream>>>((const unsigned short*)xmb, lw, lb, xlb);
  k_em_fast<<<dim3(1024), blk, 0, stream>>>((const unsigned short*)xlb, binit,
                                            (const unsigned short*)xmb, featb,
                                            gsum, gmaxu, flag);
  k_em_slowfix<<<dim3(1024), blk, 0, stream>>>((const unsigned short*)xlb, binit,
                                               (const unsigned short*)xmb, featb,
                                               gsum, gmaxu, flag);
  k_att<<<dim3(4), blk, 0, stream>>>(gsum, gmaxu, ca1, ca2, attv, out_att);
  k_fc<<<dim3(256, 2), blk, 0, stream>>>((const unsigned short*)featb, attv, fw,
                                         fb, out);
}

// Round 11
// 84.561 us; speedup vs baseline: 1.3157x; 1.0349x over previous
//
#include <hip/hip_runtime.h>
#include <hip/hip_bf16.h>
#include <math.h>

#define EPS 1e-6f
#define PITCH 72  // bf16 elems per LDS row: 64 K + 8 pad (2-way bank conflict = free)

typedef short s16x8 __attribute__((ext_vector_type(8)));
typedef float f32x4 __attribute__((ext_vector_type(4)));

__device__ __forceinline__ short bf16of(float f) {
  __hip_bfloat16 h = __float2bfloat16(f);
  return __builtin_bit_cast(short, h);
}
__device__ __forceinline__ float f32of(unsigned short u) {
  unsigned int x = ((unsigned int)u) << 16;
  return __builtin_bit_cast(float, x);
}

// ---------------------------------------------------------------------------
// K0: one-shot weight preconvert fp32 -> bf16 (w1: 32768, lw: 65536 elems).
// Grid 96 x 256 x float4 covers exactly 98304.
// ---------------------------------------------------------------------------
__global__ __launch_bounds__(256) void k_prep(const float* __restrict__ w1,
                                              const float* __restrict__ lw,
                                              short* __restrict__ w1b,
                                              short* __restrict__ lwb) {
  const int i = (blockIdx.x * 256 + threadIdx.x) * 4;
  const bool first = i < 32768;
  const float4 v = *(const float4*)(first ? w1 + i : lw + (i - 32768));
  const short4 sv = {bf16of(v.x), bf16of(v.y), bf16of(v.z), bf16of(v.w)};
  if (first)
    *(short4*)(w1b + i) = sv;
  else
    *(short4*)(lwb + (i - 32768)) = sv;
}

// ---------------------------------------------------------------------------
// K1 (MFMA): y[m][p] = sum_c x[img][c][hw] * w1[p][c].  Output bf16.
// Weight stage = pure bf16 copy from w1b. Block (0,0) zero-inits pool accums.
// ---------------------------------------------------------------------------
__global__ __launch_bounds__(256) void k_conv1x1(const float* __restrict__ x,
                                                 const unsigned short* __restrict__ w1b,
                                                 short* __restrict__ ybf,
                                                 float* __restrict__ gsum,
                                                 unsigned int* __restrict__ gmaxu) {
  __shared__ __align__(16) short Aw[128 * PITCH];  // [p][k]
  __shared__ __align__(16) short Xs[64 * PITCH];   // [m][k]
  const int t = threadIdx.x;
  if (blockIdx.x == 0 && blockIdx.y == 0) {
#pragma unroll
    for (int i = 0; i < 4; ++i) {
      gsum[t + i * 256] = 0.f;
      gmaxu[t + i * 256] = 0u;
    }
  }
  const int m0 = blockIdx.x * 64, p0 = blockIdx.y * 128;
  const int img = m0 >> 12, hw0 = m0 & 4095;
  const int lane = t & 63, w = t >> 6;
  const int lrow = lane & 15, lk = (lane >> 4) * 8;
  f32x4 acc[4][2];
#pragma unroll
  for (int i = 0; i < 4; ++i)
#pragma unroll
    for (int j = 0; j < 2; ++j) acc[i][j] = {0.f, 0.f, 0.f, 0.f};

  for (int kk = 0; kk < 128; kk += 64) {
    __syncthreads();
    {  // stage w1b rows p0..p0+127: pure copy, 32 k-elems per thread
      const int pr = t & 127, kq = t >> 7;
      const unsigned short* wp = w1b + (size_t)(p0 + pr) * 128 + kk + kq * 32;
#pragma unroll
      for (int q = 0; q < 4; ++q)
        *(s16x8*)(&Aw[pr * PITCH + kq * 32 + q * 8]) = *(const s16x8*)(wp + q * 8);
    }
    {  // stage x (c-major) -> Xs[m][c]: 4x4 register transpose + cvt
      const int m4 = (t & 15) * 4;
      const int cg = (t >> 4) * 4;
      float4 col[4];
#pragma unroll
      for (int cc = 0; cc < 4; ++cc)
        col[cc] = *(const float4*)(x + (size_t)(img * 128 + kk + cg + cc) * 4096 + hw0 + m4);
#pragma unroll
      for (int r = 0; r < 4; ++r) {
        short4 sv = {bf16of(((const float*)&col[0])[r]),
                     bf16of(((const float*)&col[1])[r]),
                     bf16of(((const float*)&col[2])[r]),
                     bf16of(((const float*)&col[3])[r])};
        *(short4*)(&Xs[(m4 + r) * PITCH + cg]) = sv;
      }
    }
    __syncthreads();
#pragma unroll
    for (int ks = 0; ks < 2; ++ks) {
      const int ko = ks * 32 + lk;
      s16x8 bfr[2];
#pragma unroll
      for (int j = 0; j < 2; ++j)
        bfr[j] = *(const s16x8*)(&Xs[(((w >> 1) * 2 + j) * 16 + lrow) * PITCH + ko]);
#pragma unroll
      for (int i = 0; i < 4; ++i) {
        const s16x8 af = *(const s16x8*)(&Aw[(((w & 1) * 4 + i) * 16 + lrow) * PITCH + ko]);
#pragma unroll
        for (int j = 0; j < 2; ++j)
          acc[i][j] = __builtin_amdgcn_mfma_f32_16x16x32_bf16(af, bfr[j], acc[i][j], 0, 0, 0);
      }
    }
  }
#pragma unroll
  for (int i = 0; i < 4; ++i) {
    const int p = p0 + ((w & 1) * 4 + i) * 16 + (lane >> 4) * 4;
#pragma unroll
    for (int j = 0; j < 2; ++j) {
      const int m = m0 + ((w >> 1) * 2 + j) * 16 + lrow;
      const f32x4 v = acc[i][j];
      short4 sv = {bf16of(v.x), bf16of(v.y), bf16of(v.z), bf16of(v.w)};
      *(short4*)(ybf + (size_t)m * 256 + p) = sv;
    }
  }
}

// ---------------------------------------------------------------------------
// K2: depthwise 3x3 SAME + bias; bf16 in, bf16 out (unchanged).
// ---------------------------------------------------------------------------
__global__ __launch_bounds__(256) void k_dwconv(const unsigned short* __restrict__ ybf,
                                                const float* __restrict__ w3,
                                                const float* __restrict__ b3,
                                                short* __restrict__ xmb) {
  __shared__ float wt[9][256];
  __shared__ float bs[256];
  const int t = threadIdx.x;
#pragma unroll
  for (int i = 0; i < 9; ++i) wt[i][t] = w3[t * 9 + i];
  bs[t] = b3[t];
  __syncthreads();
  const int sub = t >> 6;
  const int pq = t & 63;
  const int m = blockIdx.x * 4 + sub;
  const int hw = m & 4095;
  const int h = hw >> 6, ww = hw & 63;
  const int bb = m >> 12;
  float4 acc = *(const float4*)(&bs[pq * 4]);
#pragma unroll
  for (int dy = -1; dy <= 1; ++dy) {
    const int hh = h + dy;
    if (hh < 0 || hh > 63) continue;
#pragma unroll
    for (int dx = -1; dx <= 1; ++dx) {
      const int w2 = ww + dx;
      if (w2 < 0 || w2 > 63) continue;
      const int idx = (dy + 1) * 3 + (dx + 1);
      const ushort4 v =
          *(const ushort4*)(ybf + (size_t)((bb << 12) + (hh << 6) + w2) * 256 + pq * 4);
      const float4 wv = *(const float4*)(&wt[idx][pq * 4]);
      acc.x += f32of(v.x) * wv.x;
      acc.y += f32of(v.y) * wv.y;
      acc.z += f32of(v.z) * wv.z;
      acc.w += f32of(v.w) * wv.w;
    }
  }
  short4 sv = {bf16of(acc.x), bf16of(acc.y), bf16of(acc.z), bf16of(acc.w)};
  *(short4*)(xmb + (size_t)m * 256 + pq * 4) = sv;
}

// ---------------------------------------------------------------------------
// K3 (MFMA): xl = relu(xm @ lw^T + lb).  Weight stage = pure copy from lwb.
// ---------------------------------------------------------------------------
__global__ __launch_bounds__(256) void k_lower(const unsigned short* __restrict__ xmb,
                                               const unsigned short* __restrict__ lwb,
                                               const float* __restrict__ lb,
                                               short* __restrict__ xlb) {
  __shared__ __align__(16) short Aw[128 * PITCH];  // [n][k]
  __shared__ __align__(16) short Xs[64 * PITCH];   // [m][k]
  const int t = threadIdx.x;
  const int m0 = blockIdx.x * 64, n0 = blockIdx.y * 128;
  const int lane = t & 63, w = t >> 6;
  const int lrow = lane & 15, lk = (lane >> 4) * 8;
  f32x4 acc[4][2];
#pragma unroll
  for (int i = 0; i < 4; ++i)
#pragma unroll
    for (int j = 0; j < 2; ++j) acc[i][j] = {0.f, 0.f, 0.f, 0.f};

  for (int kk = 0; kk < 256; kk += 64) {
    __syncthreads();
    {  // stage lwb rows n0..n0+127: pure copy
      const int nr = t & 127, kq = t >> 7;
      const unsigned short* wp = lwb + (size_t)(n0 + nr) * 256 + kk + kq * 32;
#pragma unroll
      for (int q = 0; q < 4; ++q)
        *(s16x8*)(&Aw[nr * PITCH + kq * 32 + q * 8]) = *(const s16x8*)(wp + q * 8);
    }
    {  // stage xm: pure copy
      const int m = t & 63, q = t >> 6;
      const unsigned short* xp = xmb + (size_t)(m0 + m) * 256 + kk + q * 16;
      *(s16x8*)(&Xs[m * PITCH + q * 16]) = *(const s16x8*)(xp);
      *(s16x8*)(&Xs[m * PITCH + q * 16 + 8]) = *(const s16x8*)(xp + 8);
    }
    __syncthreads();
#pragma unroll
    for (int ks = 0; ks < 2; ++ks) {
      const int ko = ks * 32 + lk;
      s16x8 bfr[2];
#pragma unroll
      for (int j = 0; j < 2; ++j)
        bfr[j] = *(const s16x8*)(&Xs[(((w >> 1) * 2 + j) * 16 + lrow) * PITCH + ko]);
#pragma unroll
      for (int i = 0; i < 4; ++i) {
        const s16x8 af = *(const s16x8*)(&Aw[(((w & 1) * 4 + i) * 16 + lrow) * PITCH + ko]);
#pragma unroll
        for (int j = 0; j < 2; ++j)
          acc[i][j] = __builtin_amdgcn_mfma_f32_16x16x32_bf16(af, bfr[j], acc[i][j], 0, 0, 0);
      }
    }
  }
#pragma unroll
  for (int i = 0; i < 4; ++i) {
    const int n = n0 + ((w & 1) * 4 + i) * 16 + (lane >> 4) * 4;
    const float4 bias = *(const float4*)(lb + n);
#pragma unroll
    for (int j = 0; j < 2; ++j) {
      const int m = m0 + ((w >> 1) * 2 + j) * 16 + lrow;
      const f32x4 v = acc[i][j];
      short4 sv = {bf16of(fmaxf(v.x + bias.x, 0.f)), bf16of(fmaxf(v.y + bias.y, 0.f)),
                   bf16of(fmaxf(v.z + bias.z, 0.f)), bf16of(fmaxf(v.w + bias.w, 0.f))};
      *(short4*)(xlb + (size_t)m * 256 + n) = sv;
    }
  }
}

// ---------------------------------------------------------------------------
// K4a: fast EM (ILP-4) + pooling via device atomics (unchanged from r10).
// ---------------------------------------------------------------------------
__global__ __launch_bounds__(256) void k_em_fast(const unsigned short* __restrict__ xlb,
                                                 const float* __restrict__ binit,
                                                 const unsigned short* __restrict__ xmb,
                                                 short* __restrict__ featb,
                                                 float* __restrict__ gsum,
                                                 unsigned int* __restrict__ gmaxu,
                                                 int* __restrict__ flag) {
  __shared__ float psL[1024], pmL[1024];
  __shared__ int sflag;
  const int t = threadIdx.x;
  const int lane = t & 63, w = t >> 6;
  const int bid = blockIdx.x;
  const int m0 = bid * 16 + w * 4;
  bool asym = false;
#pragma unroll
  for (int p = 0; p < 4; ++p) {
    const float bv = binit[(size_t)(m0 + p) * 16 + (lane & 15)];
    const float bn = bv / fmaxf(fabsf(bv), 1e-12f);
    asym |= !__all(bn == 1.0f);
  }
  if (t == 0) sflag = 0;
  __syncthreads();
  if (asym && lane == 0) sflag = 1;
  __syncthreads();
  if (sflag) {
    if (t == 0) flag[bid] = 1;
    return;
  }

  float s[4][4], C[4][4], Bv[4];
#pragma unroll
  for (int p = 0; p < 4; ++p) {
    const ushort4 su = *(const ushort4*)(xlb + (size_t)(m0 + p) * 256 + lane * 4);
    s[p][0] = f32of(su.x);
    s[p][1] = f32of(su.y);
    s[p][2] = f32of(su.z);
    s[p][3] = f32of(su.w);
    Bv[p] = 1.f;
#pragma unroll
    for (int i = 0; i < 4; ++i) C[p][i] = 0.0625f;
  }
  for (int step = 0; step < 6; ++step) {
    float pnum[4], psq[4];
#pragma unroll
    for (int p = 0; p < 4; ++p) {
      const float k1 = 16.f * Bv[p] * Bv[p];
      pnum[p] = 0.f;
      psq[p] = 0.f;
#pragma unroll
      for (int i = 0; i < 4; ++i) {
        const float den = fmaf(C[p][i], k1, EPS);
        const float cn = C[p][i] * (s[p][i] * Bv[p]) * __builtin_amdgcn_rcpf(den);
        C[p][i] = cn;
        pnum[p] = fmaf(s[p][i], cn, pnum[p]);
        psq[p] = fmaf(cn, cn, psq[p]);
      }
    }
#pragma unroll
    for (int d = 1; d < 64; d <<= 1) {
#pragma unroll
      for (int p = 0; p < 4; ++p) {
        pnum[p] += __shfl_xor(pnum[p], d, 64);
        psq[p] += __shfl_xor(psq[p], d, 64);
      }
    }
#pragma unroll
    for (int p = 0; p < 4; ++p)
      Bv[p] = Bv[p] * pnum[p] *
              __builtin_amdgcn_rcpf(fmaf(16.f * Bv[p], psq[p], EPS));
  }
  float ps4[4] = {0.f, 0.f, 0.f, 0.f};
  float pm4[4] = {-1e30f, -1e30f, -1e30f, -1e30f};
#pragma unroll
  for (int p = 0; p < 4; ++p) {
    const ushort4 xmu = *(const ushort4*)(xmb + (size_t)(m0 + p) * 256 + lane * 4);
    const float xmv[4] = {f32of(xmu.x), f32of(xmu.y), f32of(xmu.z), f32of(xmu.w)};
    const float k1 = 16.f * Bv[p] * Bv[p];
    float o[4];
#pragma unroll
    for (int i = 0; i < 4; ++i) {
      const float den = fmaf(C[p][i], k1, EPS);
      const float cn = C[p][i] * (s[p][i] * Bv[p]) * __builtin_amdgcn_rcpf(den);
      const float xr = 16.f * Bv[p] * cn;
      o[i] = fmaxf(xmv[i] + xr, 0.f);
      ps4[i] += o[i];
      pm4[i] = fmaxf(pm4[i], o[i]);
    }
    short4 sv = {bf16of(o[0]), bf16of(o[1]), bf16of(o[2]), bf16of(o[3])};
    *(short4*)(featb + (size_t)(m0 + p) * 256 + lane * 4) = sv;
  }
#pragma unroll
  for (int i = 0; i < 4; ++i) {
    psL[w * 256 + lane * 4 + i] = ps4[i];
    pmL[w * 256 + lane * 4 + i] = pm4[i];
  }
  __syncthreads();
  const float sv = psL[t] + psL[256 + t] + psL[512 + t] + psL[768 + t];
  const float mv =
      fmaxf(fmaxf(pmL[t], pmL[256 + t]), fmaxf(pmL[512 + t], pmL[768 + t]));
  const int img = bid >> 8;
  atomicAdd(&gsum[img * 256 + t], sv);
  atomicMax(&gmaxu[img * 256 + t], __float_as_uint(mv));
  if (t == 0) flag[bid] = 0;
}

// ---------------------------------------------------------------------------
// K4b: flag-gated general-EM recompute (unchanged from r10).
// ---------------------------------------------------------------------------
__global__ __launch_bounds__(256, 2) void k_em_slowfix(
    const unsigned short* __restrict__ xlb, const float* __restrict__ binit,
    const unsigned short* __restrict__ xmb, short* __restrict__ featb,
    float* __restrict__ gsum, unsigned int* __restrict__ gmaxu,
    const int* __restrict__ flag) {
  const int bid = blockIdx.x;
  if (flag[bid] == 0) return;
  __shared__ float psL[1024], pmL[1024];
  const int t = threadIdx.x;
  const int lane = t & 63, w = t >> 6;
  const int m0 = bid * 16 + w * 4;
  float ps4[4] = {0.f, 0.f, 0.f, 0.f};
  float pm4[4] = {-1e30f, -1e30f, -1e30f, -1e30f};
  for (int p = 0; p < 4; ++p) {
    const int m = m0 + p;
    const ushort4 su = *(const ushort4*)(xlb + (size_t)m * 256 + lane * 4);
    const float s[4] = {f32of(su.x), f32of(su.y), f32of(su.z), f32of(su.w)};
    float b[16];
#pragma unroll
    for (int r = 0; r < 16; ++r) {
      const float v = binit[(size_t)m * 16 + r];
      b[r] = v / fmaxf(fabsf(v), 1e-12f);
    }
    float c[4][16];
#pragma unroll
    for (int i = 0; i < 4; ++i) {
      float mx = s[i] * b[0];
#pragma unroll
      for (int r = 1; r < 16; ++r) mx = fmaxf(mx, s[i] * b[r]);
      float sum = 0.f;
#pragma unroll
      for (int r = 0; r < 16; ++r) {
        const float e = __expf(s[i] * b[r] - mx);
        c[i][r] = e;
        sum += e;
      }
      const float inv = __fdividef(1.f, sum);
#pragma unroll
      for (int r = 0; r < 16; ++r) c[i][r] *= inv;
    }
    for (int step = 0; step < 6; ++step) {
      float red[32];
#pragma unroll
      for (int r = 0; r < 32; ++r) red[r] = 0.f;
#pragma unroll
      for (int i = 0; i < 4; ++i) {
        float tt = 0.f;
#pragma unroll
        for (int r = 0; r < 16; ++r) tt += c[i][r] * b[r];
        float tp = 0.f;
#pragma unroll
        for (int r = 0; r < 16; ++r) {
          const float cn = c[i][r] * (s[i] * b[r]) * __frcp_rn(tt * b[r] + EPS);
          c[i][r] = cn;
          tp += cn * b[r];
          red[r] += s[i] * cn;
        }
#pragma unroll
        for (int r = 0; r < 16; ++r) red[16 + r] += tp * c[i][r];
      }
      int cnt = 32;
#pragma unroll
      for (int k = 4; k >= 0; --k) {
        const int d = 1 << k;
        const bool up = (lane >> k) & 1;
        const int half = cnt >> 1;
#pragma unroll
        for (int j = 0; j < half; ++j) {
          const float lo = red[j], hi = red[j + half];
          const float send = up ? lo : hi;
          const float recv = __shfl_xor(send, d, 64);
          red[j] = (up ? hi : lo) + recv;
        }
        cnt = half;
      }
      float S = red[0] + __shfl_xor(red[0], 32, 64);
      const float dpart = __shfl_xor(S, 16, 64);
      const float q = S * __frcp_rn(dpart + EPS);
#pragma unroll
      for (int r = 0; r < 16; ++r) b[r] *= __shfl(q, r, 64);
    }
    const ushort4 xmu = *(const ushort4*)(xmb + (size_t)m * 256 + lane * 4);
    const float xmv[4] = {f32of(xmu.x), f32of(xmu.y), f32of(xmu.z), f32of(xmu.w)};
    float o4[4];
#pragma unroll
    for (int i = 0; i < 4; ++i) {
      float tt = 0.f;
#pragma unroll
      for (int r = 0; r < 16; ++r) tt += c[i][r] * b[r];
      float xr = 0.f;
#pragma unroll
      for (int r = 0; r < 16; ++r) {
        const float cn = c[i][r] * (s[i] * b[r]) * __frcp_rn(tt * b[r] + EPS);
        xr += b[r] * cn;
      }
      o4[i] = fmaxf(xmv[i] + xr, 0.f);
      ps4[i] += o4[i];
      pm4[i] = fmaxf(pm4[i], o4[i]);
    }
    short4 sv = {bf16of(o4[0]), bf16of(o4[1]), bf16of(o4[2]), bf16of(o4[3])};
    *(short4*)(featb + (size_t)m * 256 + lane * 4) = sv;
  }
#pragma unroll
  for (int i = 0; i < 4; ++i) {
    psL[w * 256 + lane * 4 + i] = ps4[i];
    pmL[w * 256 + lane * 4 + i] = pm4[i];
  }
  __syncthreads();
  const float sv = psL[t] + psL[256 + t] + psL[512 + t] + psL[768 + t];
  const float mv =
      fmaxf(fmaxf(pmL[t], pmL[256 + t]), fmaxf(pmL[512 + t], pmL[768 + t]));
  const int img = bid >> 8;
  atomicAdd(&gsum[img * 256 + t], sv);
  atomicMax(&gmaxu[img * 256 + t], __float_as_uint(mv));
}

// ---------------------------------------------------------------------------
// K5: channel-attention MLP + sigmoid; also writes att-scaled bf16 weights
// fwab[img][o][k] = bf16(fw[o][k] * att[img][k]) for k_fc (coalesced).
// ---------------------------------------------------------------------------
__global__ __launch_bounds__(256) void k_att(const float* __restrict__ gsum,
                                             const unsigned int* __restrict__ gmaxu,
                                             const float* __restrict__ ca1,
                                             const float* __restrict__ ca2,
                                             const float* __restrict__ fw,
                                             short* __restrict__ fwab,
                                             float* __restrict__ out_att) {
  __shared__ float fA[256], fM[256], sH[64], attL[256];
  const int t = threadIdx.x;
  const int b = blockIdx.x;
  fA[t] = gsum[b * 256 + t] * (1.0f / 4096.0f);
  fM[t] = __uint_as_float(gmaxu[b * 256 + t]);
  __syncthreads();
  if (t < 64) {
    float ha = 0.f, hm = 0.f;
#pragma unroll 8
    for (int p = 0; p < 256; ++p) {
      const float wv = ca1[t * 256 + p];
      ha += fA[p] * wv;
      hm += fM[p] * wv;
    }
    sH[t] = fmaxf(ha, 0.f) + fmaxf(hm, 0.f);
  }
  __syncthreads();
  float logit = 0.f;
#pragma unroll 8
  for (int a = 0; a < 64; ++a) logit += sH[a] * ca2[t * 64 + a];
  const float av = 1.0f / (1.0f + expf(-logit));
  attL[t] = av;
  out_att[b * 256 + t] = av;
  __syncthreads();
  // fwab: 128 o x 256 k = 32768 elems; lane-coalesced float4 sweep.
  const int k0 = (t * 4) & 255;
  const float a0 = attL[k0], a1 = attL[k0 + 1], a2 = attL[k0 + 2], a3 = attL[k0 + 3];
  const int base = b * 32768;
#pragma unroll 4
  for (int j = 0; j < 32; ++j) {
    const int idx = t * 4 + j * 1024;
    const float4 v = *(const float4*)(fw + idx);
    const short4 sv = {bf16of(v.x * a0), bf16of(v.y * a1), bf16of(v.z * a2),
                       bf16of(v.w * a3)};
    *(short4*)(&fwab[base + idx]) = sv;
  }
}

// ---------------------------------------------------------------------------
// K6 (MFMA): out = feat @ fwab[img]^T + fb.  Both stages pure bf16 copies.
// ---------------------------------------------------------------------------
__global__ __launch_bounds__(256) void k_fc(const unsigned short* __restrict__ featb,
                                            const unsigned short* __restrict__ fwab,
                                            const float* __restrict__ fb,
                                            float* __restrict__ out) {
  __shared__ __align__(16) short Fs[64 * PITCH];  // [m][k]
  __shared__ __align__(16) short Ws[64 * PITCH];  // [o][k]
  const int t = threadIdx.x;
  const int m0 = blockIdx.x * 64, o0 = blockIdx.y * 64;
  const int img = m0 >> 12, hw0 = m0 & 4095;
  const int lane = t & 63, w = t >> 6;
  const int lrow = lane & 15, lk = (lane >> 4) * 8;
  f32x4 acc[2][2];
#pragma unroll
  for (int i = 0; i < 2; ++i)
#pragma unroll
    for (int j = 0; j < 2; ++j) acc[i][j] = {0.f, 0.f, 0.f, 0.f};

  const unsigned short* fwimg = fwab + (size_t)img * 32768;
  for (int kk = 0; kk < 256; kk += 64) {
    __syncthreads();
    {  // stage feat: pure copy
      const int m = t & 63, q = t >> 6;
      const unsigned short* fp = featb + (size_t)(m0 + m) * 256 + kk + q * 16;
      *(s16x8*)(&Fs[m * PITCH + q * 16]) = *(const s16x8*)(fp);
      *(s16x8*)(&Fs[m * PITCH + q * 16 + 8]) = *(const s16x8*)(fp + 8);
    }
    {  // stage fwab rows o0..o0+63: pure copy
      const int o = t & 63, q = t >> 6;
      const unsigned short* wp = fwimg + (size_t)(o0 + o) * 256 + kk + q * 16;
      *(s16x8*)(&Ws[o * PITCH + q * 16]) = *(const s16x8*)(wp);
      *(s16x8*)(&Ws[o * PITCH + q * 16 + 8]) = *(const s16x8*)(wp + 8);
    }
    __syncthreads();
#pragma unroll
    for (int ks = 0; ks < 2; ++ks) {
      const int ko = ks * 32 + lk;
      s16x8 af[2];
#pragma unroll
      for (int i = 0; i < 2; ++i)
        af[i] = *(const s16x8*)(&Fs[(((w >> 1) * 2 + i) * 16 + lrow) * PITCH + ko]);
#pragma unroll
      for (int j = 0; j < 2; ++j) {
        const s16x8 bfr = *(const s16x8*)(&Ws[(((w & 1) * 2 + j) * 16 + lrow) * PITCH + ko]);
#pragma unroll
        for (int i = 0; i < 2; ++i)
          acc[i][j] = __builtin_amdgcn_mfma_f32_16x16x32_bf16(af[i], bfr, acc[i][j], 0, 0, 0);
      }
    }
  }
#pragma unroll
  for (int j = 0; j < 2; ++j) {
    const int o = o0 + ((w & 1) * 2 + j) * 16 + lrow;
    const float bias = fb[o];
#pragma unroll
    for (int i = 0; i < 2; ++i) {
      const int hw = hw0 + ((w >> 1) * 2 + i) * 16 + (lane >> 4) * 4;
      f32x4 v = acc[i][j];
      v.x += bias;
      v.y += bias;
      v.z += bias;
      v.w += bias;
      *(f32x4*)(out + (size_t)img * 524288 + (size_t)o * 4096 + hw) = v;
    }
  }
}

extern "C" void kernel_launch(void* const* d_in, const int* in_sizes, int n_in,
                              void* d_out, int out_size, void* d_ws, size_t ws_size,
                              hipStream_t stream) {
  const float* x = (const float*)d_in[0];
  const float* w1 = (const float*)d_in[1];
  const float* w3 = (const float*)d_in[2];
  const float* b3 = (const float*)d_in[3];
  const float* lw = (const float*)d_in[4];
  const float* lb = (const float*)d_in[5];
  const float* ca1 = (const float*)d_in[6];
  const float* ca2 = (const float*)d_in[7];
  const float* fw = (const float*)d_in[8];
  const float* fb = (const float*)d_in[9];
  const float* binit = (const float*)d_in[10];

  char* wsb = (char*)d_ws;
  short* ybf = (short*)wsb;                        // 8 MB bf16
  short* xmb = (short*)(wsb + (8u << 20));         // 8 MB bf16
  short* xlb = (short*)(wsb + (16u << 20));        // 8 MB bf16
  short* featb = (short*)(wsb + (24u << 20));      // 8 MB bf16
  float* gsum = (float*)(wsb + (32u << 20));       // 4 KB
  unsigned int* gmaxu = (unsigned int*)(wsb + (33u << 20));  // 4 KB
  int* flag = (int*)(wsb + (34u << 20));           // 4 KB
  short* w1b = (short*)(wsb + (35u << 20));        // 64 KB
  short* lwb = (short*)(wsb + (36u << 20));        // 128 KB
  short* fwab = (short*)(wsb + (37u << 20));       // 256 KB
  float* out = (float*)d_out;
  float* out_att = out + 2097152;

  const dim3 blk(256);
  k_prep<<<dim3(96), blk, 0, stream>>>(w1, lw, w1b, lwb);
  k_conv1x1<<<dim3(256, 2), blk, 0, stream>>>(x, (const unsigned short*)w1b, ybf,
                                              gsum, gmaxu);
  k_dwconv<<<dim3(4096), blk, 0, stream>>>((const unsigned short*)ybf, w3, b3, xmb);
  k_lower<<<dim3(256, 2), blk, 0, stream>>>((const unsigned short*)xmb,
                                            (const unsigned short*)lwb, lb, xlb);
  k_em_fast<<<dim3(1024), blk, 0, stream>>>((const unsigned short*)xlb, binit,
                                            (const unsigned short*)xmb, featb,
                                            gsum, gmaxu, flag);
  k_em_slowfix<<<dim3(1024), blk, 0, stream>>>((const unsigned short*)xlb, binit,
                                               (const unsigned short*)xmb, featb,
                                               gsum, gmaxu, flag);
  k_att<<<dim3(4), blk, 0, stream>>>(gsum, gmaxu, ca1, ca2, fw, fwab, out_att);
  k_fc<<<dim3(256, 2), blk, 0, stream>>>((const unsigned short*)featb,
                                         (const unsigned short*)fwab, fb, out);
}